// Round 1
// 84.774 us; speedup vs baseline: 1.0217x; 1.0217x over previous
//
#include <hip/hip_runtime.h>
#include <math.h>

#define N 256
#define D 512
#define SPLIT 4

using f32x4  = __attribute__((ext_vector_type(4))) float;
using bf16x8 = __attribute__((ext_vector_type(8))) short;

// f32 -> bf16 via native __bf16 cast: compiler emits v_cvt_pk_bf16_f32 (RTNE)
// for adjacent pairs (m240: scalar cast beats hand-written cvt_pk asm, and
// both beat the 5-op bit-twiddle previously used here).
__device__ __forceinline__ short f2bf(float f) {
    __bf16 h = (__bf16)f;
    return __builtin_bit_cast(short, h);
}

__device__ __forceinline__ float smooth_l1(float x) {
    float ax = fabsf(x);
    return ax < 1.f ? 0.5f * ax * ax : ax - 0.5f;
}

// A&S 4.4.45: |err| <= 5e-5 on [-1,1]; loss threshold is 1.47e-2 -> safe.
__device__ __forceinline__ float acos_fast(float x) {
    float ax = fabsf(x);
    float p = -0.0187293f;
    p = p * ax + 0.0742610f;
    p = p * ax - 0.2121144f;
    p = p * ax + 1.5707288f;
    float v = sqrtf(1.f - ax) * p;
    return x < 0.f ? 3.14159265358979f - v : v;
}

// ---------------------------------------------------------------------------
// MFMA Gram: G = E * E^T via bf16 16x16x32 matrix cores. One wave per 16x16
// output tile, grid (16,16,2) [z: 0=student,1=teacher], block 64 (1 wave).
// G is exactly symmetric (same product multiset through the same MFMA
// reduction tree), so tiles with by>bx exit immediately and by<bx tiles
// mirror-write the transposed tile: ~2x less gram compute, identical bits.
// C/D layout col=lane&15, row=(lane>>4)*4+reg (verified m89/m91).
// G stored interleaved float2 (x=student, y=teacher).
//
// STRUCTURE NOTES (measured prior session):
//  - 3 small dispatches is the floor. cg::grid_sync costs ~95us/sync (R6);
//    per-block __threadfence finalize costs +20us (R3). Keep 3 launches.
// ---------------------------------------------------------------------------
__global__ __launch_bounds__(64) void gram_kernel(const float* __restrict__ Es,
                                                  const float* __restrict__ Et,
                                                  float2* __restrict__ G2,
                                                  float* __restrict__ acc) {
    const int lane = threadIdx.x;
    if (blockIdx.x == 0 && blockIdx.y == 0 && blockIdx.z == 0 && lane == 0) {
        acc[0] = 0.f;   // dist sum
        acc[1] = 0.f;   // angle sum
    }
    if (blockIdx.y > blockIdx.x) return;   // lower triangle comes from mirror

    const float* E = blockIdx.z ? Et : Es;
    const int m = lane & 15, quad = lane >> 4;
    const int baseA = (blockIdx.y * 16 + m) * D + quad * 8;
    const int baseB = (blockIdx.x * 16 + m) * D + quad * 8;

    f32x4 c = {0.f, 0.f, 0.f, 0.f};
#pragma unroll
    for (int k0 = 0; k0 < D; k0 += 32) {
        float4 alo = *(const float4*)&E[baseA + k0];
        float4 ahi = *(const float4*)&E[baseA + k0 + 4];
        float4 blo = *(const float4*)&E[baseB + k0];
        float4 bhi = *(const float4*)&E[baseB + k0 + 4];
        bf16x8 a, b;
        a[0] = f2bf(alo.x); a[1] = f2bf(alo.y); a[2] = f2bf(alo.z); a[3] = f2bf(alo.w);
        a[4] = f2bf(ahi.x); a[5] = f2bf(ahi.y); a[6] = f2bf(ahi.z); a[7] = f2bf(ahi.w);
        b[0] = f2bf(blo.x); b[1] = f2bf(blo.y); b[2] = f2bf(blo.z); b[3] = f2bf(blo.w);
        b[4] = f2bf(bhi.x); b[5] = f2bf(bhi.y); b[6] = f2bf(bhi.z); b[7] = f2bf(bhi.w);
        c = __builtin_amdgcn_mfma_f32_16x16x32_bf16(a, b, c, 0, 0, 0);
    }

    const int col = blockIdx.x * 16 + m;
    const bool mirror = blockIdx.y < blockIdx.x;
#pragma unroll
    for (int r = 0; r < 4; ++r) {
        const int row = blockIdx.y * 16 + quad * 4 + r;
        ((float*)&G2[row * N + col])[blockIdx.z] = c[r];
        if (mirror)
            ((float*)&G2[col * N + row])[blockIdx.z] = c[r];
    }
}

// ---------------------------------------------------------------------------
// Fused angle + distance loss.  grid (255, SPLIT), block 256.  j = bx + 1.
// dot = G[i,k] - G[i,j] - G[k,j] + G[j,j];  |e_a-e_j|^2 = G[a,a]-2G[a,j]+G[j,j].
// eps_pd correction (~2e-6 on loss) dropped; eps_cos floor unreachable.
// sv/tv merged into one float4 LDS array (one b128 gather per index instead
// of two b64); block reduction via 64-lane shuffle (1 barrier, not 8).
// ---------------------------------------------------------------------------
__global__ __launch_bounds__(256) void angle_dist_kernel(const float2* __restrict__ G2,
                                                         float* __restrict__ acc) {
    const int j = blockIdx.x + 1;   // 1..255
    const int tid = threadIdx.x;
    __shared__ float4 stv[N];       // (Gs[a,j], 1/|s_a-s_j|, Gt[a,j], 1/|t_a-t_j|)
    __shared__ float2 red[4];
    const float2 gjj = G2[j * N + j];
    const float Gsjj = gjj.x, Gtjj = gjj.y;

    float distp = 0.f;
    {
        const int a = tid;
        float2 gaj = G2[a * N + j];
        float2 gaa = G2[a * N + a];
        float n2s = gaa.x - 2.f * gaj.x + Gsjj;
        float n2t = gaa.y - 2.f * gaj.y + Gtjj;
        float rs = (a == j) ? 0.f : rsqrtf(n2s);
        float rt = (a == j) ? 0.f : rsqrtf(n2t);
        stv[a] = make_float4(gaj.x, rs, gaj.y, rt);
        if (blockIdx.y == 0 && a < j)
            distp = smooth_l1(n2s * rs - n2t * rt);   // sqrt(x) = x * rsqrt(x)
    }
    __syncthreads();

    const int nk = 255 - j;          // k in [j+1, 255]
    const int npairs = j * nk;       // i in [0, j)
    const float inv_nk = 1.0f / (float)nk;
    const float lo = -0.99999994f;
    const float hi = 0.99999994f;

    float anglep = 0.f;
    for (int p = blockIdx.y * 256 + tid; p < npairs; p += 256 * SPLIT) {
        int i = (int)((float)p * inv_nk);
        int rem = p - i * nk;
        if (rem < 0) { --i; rem += nk; }
        else if (rem >= nk) { ++i; rem -= nk; }
        const int k = j + 1 + rem;
        float4 si = stv[i], sk = stv[k];
        float2 gik = G2[i * N + k];
        float dots = gik.x - si.x - sk.x + Gsjj;
        float dott = gik.y - si.z - sk.z + Gtjj;
        float coss = fminf(fmaxf(dots * (si.y * sk.y), lo), hi);
        float cost = fminf(fmaxf(dott * (si.w * sk.w), lo), hi);
        anglep += smooth_l1(acos_fast(coss) - acos_fast(cost));
    }

    // 64-lane shuffle reduce, then 4 wave partials through LDS.
    float vx = distp, vy = anglep;
#pragma unroll
    for (int off = 32; off > 0; off >>= 1) {
        vx += __shfl_down(vx, off);
        vy += __shfl_down(vy, off);
    }
    if ((tid & 63) == 0) red[tid >> 6] = make_float2(vx, vy);
    __syncthreads();
    if (tid == 0) {
        float rx = red[0].x + red[1].x + red[2].x + red[3].x;
        float ry = red[0].y + red[1].y + red[2].y + red[3].y;
        atomicAdd(&acc[1], ry);
        if (blockIdx.y == 0) atomicAdd(&acc[0], rx);
    }
}

__global__ void finalize_kernel(const float* __restrict__ acc,
                                float* __restrict__ out) {
    float dl = 2.f * acc[0] / (float)(N * N);                 // mean over full n x n
    float al = acc[1] / (float)(N * (N - 1) * (N - 2) / 6);   // C(n,3) triplets
    out[0] = 1.0f * dl + 2.0f * al;
    out[1] = dl;
    out[2] = al;
}

extern "C" void kernel_launch(void* const* d_in, const int* in_sizes, int n_in,
                              void* d_out, int out_size, void* d_ws, size_t ws_size,
                              hipStream_t stream) {
    const float* Es = (const float*)d_in[0];
    const float* Et = (const float*)d_in[1];
    float* out = (float*)d_out;
    float* ws = (float*)d_ws;

    float* acc = ws;                      // [0]=dist, [1]=angle
    float2* G2 = (float2*)(ws + 64);      // N*N float2 (x=student, y=teacher)

    gram_kernel<<<dim3(16, 16, 2), 64, 0, stream>>>(Es, Et, G2, acc);
    angle_dist_kernel<<<dim3(N - 1, SPLIT), 256, 0, stream>>>(G2, acc);
    finalize_kernel<<<1, 1, 0, stream>>>(acc, out);
}

// Round 2
// 84.212 us; speedup vs baseline: 1.0285x; 1.0067x over previous
//
#include <hip/hip_runtime.h>
#include <math.h>

#define N 256
#define D 512
#define SPLIT 4

using f32x4  = __attribute__((ext_vector_type(4))) float;
using bf16x8 = __attribute__((ext_vector_type(8))) short;

// f32 -> bf16 via native __bf16 cast: compiler emits v_cvt_pk_bf16_f32 (RTNE)
// for adjacent pairs (m240).
__device__ __forceinline__ short f2bf(float f) {
    __bf16 h = (__bf16)f;
    return __builtin_bit_cast(short, h);
}

__device__ __forceinline__ bf16x8 cvt8(float4 lo, float4 hi) {
    bf16x8 v;
    v[0] = f2bf(lo.x); v[1] = f2bf(lo.y); v[2] = f2bf(lo.z); v[3] = f2bf(lo.w);
    v[4] = f2bf(hi.x); v[5] = f2bf(hi.y); v[6] = f2bf(hi.z); v[7] = f2bf(hi.w);
    return v;
}

__device__ __forceinline__ float smooth_l1(float x) {
    float ax = fabsf(x);
    return ax < 1.f ? 0.5f * ax * ax : ax - 0.5f;
}

// A&S 4.4.45: |err| <= 5e-5 on [-1,1]; loss threshold is 1.47e-2 -> safe.
__device__ __forceinline__ float acos_fast(float x) {
    float ax = fabsf(x);
    float p = -0.0187293f;
    p = p * ax + 0.0742610f;
    p = p * ax - 0.2121144f;
    p = p * ax + 1.5707288f;
    float v = sqrtf(1.f - ax) * p;
    return x < 0.f ? 3.14159265358979f - v : v;
}

// ---------------------------------------------------------------------------
// MFMA Gram: G = E * E^T. One wave per 32x32 output region (2x2 grid of
// 16x16x32 MFMA tiles, register-blocked so each converted bf16 fragment is
// used twice). Triangular-linearized grid: 36 upper tiles x 2 (z=s/t), all
// blocks live. G symmetric -> off-diagonal tiles mirror-write the transpose
// (identical bits: same product multiset, same MFMA reduction tree).
// Verified layouts only: A[m=lane&15][k=(lane>>4)*8+j]; C/D col=lane&15,
// row=(lane>>4)*4+reg (m89/m91). G stored interleaved float2 (x=s, y=t).
//
// STRUCTURE NOTES (measured prior sessions):
//  - 3 dispatches is the floor: cg::grid_sync ~95us/sync; threadfence
//    finalize +20us. Keep separate launches.
//  - Measured window is dominated by ~2x 40us harness poison fills (256 MiB
//    at ~84% HBM peak); kernel share is ~5us total.
// ---------------------------------------------------------------------------
__global__ __launch_bounds__(64) void gram_kernel(const float* __restrict__ Es,
                                                  const float* __restrict__ Et,
                                                  float2* __restrict__ G2,
                                                  float* __restrict__ acc) {
    const int lane = threadIdx.x;
    const int t = blockIdx.x;                 // 0..35 triangular tile id (8x8)
    if (t == 0 && blockIdx.z == 0 && lane == 0) {
        acc[0] = 0.f;   // dist sum
        acc[1] = 0.f;   // angle sum
    }
    // decode t -> (bx, by) with by <= bx  (row tile = by, col tile = bx)
    int bx = (int)((sqrtf(8.f * (float)t + 1.f) - 1.f) * 0.5f);
    if ((bx + 1) * (bx + 2) / 2 <= t) ++bx;
    else if (bx * (bx + 1) / 2 > t) --bx;
    const int by = t - bx * (bx + 1) / 2;

    const float* E = blockIdx.z ? Et : Es;
    const int m = lane & 15, quad = lane >> 4;
    const int baseA0 = (by * 32 + m) * D + quad * 8;        // rows by*32 +  0..15
    const int baseA1 = baseA0 + 16 * D;                     // rows by*32 + 16..31
    const int baseB0 = (bx * 32 + m) * D + quad * 8;        // cols bx*32 +  0..15
    const int baseB1 = baseB0 + 16 * D;

    f32x4 c00 = {0.f, 0.f, 0.f, 0.f};
    f32x4 c01 = c00, c10 = c00, c11 = c00;
#pragma unroll
    for (int k0 = 0; k0 < D; k0 += 32) {
        bf16x8 a0 = cvt8(*(const float4*)&E[baseA0 + k0], *(const float4*)&E[baseA0 + k0 + 4]);
        bf16x8 a1 = cvt8(*(const float4*)&E[baseA1 + k0], *(const float4*)&E[baseA1 + k0 + 4]);
        bf16x8 b0 = cvt8(*(const float4*)&E[baseB0 + k0], *(const float4*)&E[baseB0 + k0 + 4]);
        bf16x8 b1 = cvt8(*(const float4*)&E[baseB1 + k0], *(const float4*)&E[baseB1 + k0 + 4]);
        c00 = __builtin_amdgcn_mfma_f32_16x16x32_bf16(a0, b0, c00, 0, 0, 0);
        c01 = __builtin_amdgcn_mfma_f32_16x16x32_bf16(a0, b1, c01, 0, 0, 0);
        c10 = __builtin_amdgcn_mfma_f32_16x16x32_bf16(a1, b0, c10, 0, 0, 0);
        c11 = __builtin_amdgcn_mfma_f32_16x16x32_bf16(a1, b1, c11, 0, 0, 0);
    }

    const bool mirror = by < bx;
    const int rowb = by * 32 + quad * 4;
    const int colb = bx * 32 + m;
    const int z = blockIdx.z;
#pragma unroll
    for (int sa = 0; sa < 2; ++sa) {
#pragma unroll
        for (int sb = 0; sb < 2; ++sb) {
            const f32x4 c = (sa == 0) ? (sb == 0 ? c00 : c01)
                                      : (sb == 0 ? c10 : c11);
            const int col = colb + sb * 16;
#pragma unroll
            for (int r = 0; r < 4; ++r) {
                const int row = rowb + sa * 16 + r;
                ((float*)&G2[row * N + col])[z] = c[r];
                if (mirror)
                    ((float*)&G2[col * N + row])[z] = c[r];
            }
        }
    }
}

// ---------------------------------------------------------------------------
// Fused angle + distance loss.  grid (255, SPLIT), block 256.  j = bx + 1.
// dot = G[i,k] - G[i,j] - G[k,j] + G[j,j];  |e_a-e_j|^2 = G[a,a]-2G[a,j]+G[j,j].
// eps_pd correction (~2e-6 on loss) dropped; eps_cos floor unreachable.
// stv: one float4 LDS gather per index; block reduce via 64-lane shuffle.
// ---------------------------------------------------------------------------
__global__ __launch_bounds__(256) void angle_dist_kernel(const float2* __restrict__ G2,
                                                         float* __restrict__ acc) {
    const int j = blockIdx.x + 1;   // 1..255
    const int tid = threadIdx.x;
    __shared__ float4 stv[N];       // (Gs[a,j], 1/|s_a-s_j|, Gt[a,j], 1/|t_a-t_j|)
    __shared__ float2 red[4];
    const float2 gjj = G2[j * N + j];
    const float Gsjj = gjj.x, Gtjj = gjj.y;

    float distp = 0.f;
    {
        const int a = tid;
        float2 gaj = G2[a * N + j];
        float2 gaa = G2[a * N + a];
        float n2s = gaa.x - 2.f * gaj.x + Gsjj;
        float n2t = gaa.y - 2.f * gaj.y + Gtjj;
        float rs = (a == j) ? 0.f : rsqrtf(n2s);
        float rt = (a == j) ? 0.f : rsqrtf(n2t);
        stv[a] = make_float4(gaj.x, rs, gaj.y, rt);
        if (blockIdx.y == 0 && a < j)
            distp = smooth_l1(n2s * rs - n2t * rt);   // sqrt(x) = x * rsqrt(x)
    }
    __syncthreads();

    const int nk = 255 - j;          // k in [j+1, 255]
    const int npairs = j * nk;       // i in [0, j)
    const float inv_nk = 1.0f / (float)nk;
    const float lo = -0.99999994f;
    const float hi = 0.99999994f;

    float anglep = 0.f;
    for (int p = blockIdx.y * 256 + tid; p < npairs; p += 256 * SPLIT) {
        int i = (int)((float)p * inv_nk);
        int rem = p - i * nk;
        if (rem < 0) { --i; rem += nk; }
        else if (rem >= nk) { ++i; rem -= nk; }
        const int k = j + 1 + rem;
        float4 si = stv[i], sk = stv[k];
        float2 gik = G2[i * N + k];
        float dots = gik.x - si.x - sk.x + Gsjj;
        float dott = gik.y - si.z - sk.z + Gtjj;
        float coss = fminf(fmaxf(dots * (si.y * sk.y), lo), hi);
        float cost = fminf(fmaxf(dott * (si.w * sk.w), lo), hi);
        anglep += smooth_l1(acos_fast(coss) - acos_fast(cost));
    }

    // 64-lane shuffle reduce, then 4 wave partials through LDS.
    float vx = distp, vy = anglep;
#pragma unroll
    for (int off = 32; off > 0; off >>= 1) {
        vx += __shfl_down(vx, off);
        vy += __shfl_down(vy, off);
    }
    if ((tid & 63) == 0) red[tid >> 6] = make_float2(vx, vy);
    __syncthreads();
    if (tid == 0) {
        float rx = red[0].x + red[1].x + red[2].x + red[3].x;
        float ry = red[0].y + red[1].y + red[2].y + red[3].y;
        atomicAdd(&acc[1], ry);
        if (blockIdx.y == 0) atomicAdd(&acc[0], rx);
    }
}

__global__ void finalize_kernel(const float* __restrict__ acc,
                                float* __restrict__ out) {
    float dl = 2.f * acc[0] / (float)(N * N);                 // mean over full n x n
    float al = acc[1] / (float)(N * (N - 1) * (N - 2) / 6);   // C(n,3) triplets
    out[0] = 1.0f * dl + 2.0f * al;
    out[1] = dl;
    out[2] = al;
}

extern "C" void kernel_launch(void* const* d_in, const int* in_sizes, int n_in,
                              void* d_out, int out_size, void* d_ws, size_t ws_size,
                              hipStream_t stream) {
    const float* Es = (const float*)d_in[0];
    const float* Et = (const float*)d_in[1];
    float* out = (float*)d_out;
    float* ws = (float*)d_ws;

    float* acc = ws;                      // [0]=dist, [1]=angle
    float2* G2 = (float2*)(ws + 64);      // N*N float2 (x=student, y=teacher)

    gram_kernel<<<dim3(36, 1, 2), 64, 0, stream>>>(Es, Et, G2, acc);
    angle_dist_kernel<<<dim3(N - 1, SPLIT), 256, 0, stream>>>(G2, acc);
    finalize_kernel<<<1, 1, 0, stream>>>(acc, out);
}